// Round 10
// baseline (622.737 us; speedup 1.0000x reference)
//
#include <hip/hip_runtime.h>
#include <math.h>

#define BB   4096
#define SS   5
#define DD   64
#define HSZ  961
#define VSA  1024
#define NT   256
#define NB   2      // batches per block, packed pairwise (v2f = (nb0,nb1))
#define LNE  1e-3f

// padded h layout: P[r] = h[r-POFF] for r in [POFF, POFF+960], else 0
#define POFF 64
#define PW   1092   // max index accessed = 1091 (incl. +1-iter prefetch); 16B rows

typedef float v4f __attribute__((ext_vector_type(4)));   // native vec for nontemporal
typedef float v2f __attribute__((ext_vector_type(2)));   // packed pair (nb0,nb1)

__device__ __forceinline__ float rcp_f(float x) { return __builtin_amdgcn_rcpf(x); }
__device__ __forceinline__ float silu_f(float x) { return x * rcp_f(1.f + __expf(-x)); }
__device__ __forceinline__ v2f splat2(float x) { v2f r; r.x = x; r.y = x; return r; }
__device__ __forceinline__ v2f fma2(v2f a, float b, v2f c) {
    return __builtin_elementwise_fma(a, splat2(b), c);   // v_pk_fma_f32
}
__device__ __forceinline__ v2f fma2v(v2f a, v2f b, v2f c) {
    return __builtin_elementwise_fma(a, b, c);
}
__device__ __forceinline__ v2f silu2(v2f x) {            // both nb at once
    v2f e; e.x = __expf(-x.x); e.y = __expf(-x.y);
    v2f d = e + splat2(1.f);
    v2f rc; rc.x = rcp_f(d.x); rc.y = rcp_f(d.y);
    return x * rc;
}
// component select with compile-time nb (all uses under full unroll)
__device__ __forceinline__ float c2(v2f v, int nb) { return nb == 0 ? v.x : v.y; }

// ---- DPP wave64 sum: pure-VALU reduction, no lgkmcnt traffic ----
template <int CTRL>
__device__ __forceinline__ float dpp_add(float x) {
    int t = __builtin_amdgcn_update_dpp(0, __builtin_bit_cast(int, x),
                                        CTRL, 0xf, 0xf, false);
    return x + __builtin_bit_cast(float, t);
}
__device__ __forceinline__ float wave64_sum_l63(float x) {
    x = dpp_add<0x111>(x);  // row_shr:1
    x = dpp_add<0x112>(x);  // row_shr:2
    x = dpp_add<0x114>(x);  // row_shr:4
    x = dpp_add<0x118>(x);  // row_shr:8
    x = dpp_add<0x142>(x);  // row_bcast:15
    x = dpp_add<0x143>(x);  // row_bcast:31
    return x;
}

// ---- Kernel 1: sp = LN(silu(conv(symbols,h))); also emit zero-padded h ----
__global__ __launch_bounds__(NT)
void sp_kernel(const float* __restrict__ symbols, const float* __restrict__ h,
               const float* __restrict__ gamma, const float* __restrict__ beta,
               float* __restrict__ sp, float* __restrict__ hpadG)
{
    __shared__ float hpad[PW];
    __shared__ float red[4][2];
    const int s = blockIdx.x;
    const int tid = threadIdx.x;
    const int lane = tid & 63, wave = tid >> 6;

    for (int r = tid; r < PW; r += NT) {
        const float v = (r >= POFF && r <= POFF + 960) ? h[s * HSZ + (r - POFF)] : 0.f;
        hpad[r] = v;
        hpadG[s * PW + r] = v;        // padded copy for main_kernel
    }
    __syncthreads();

    const int base = 1020 - 4 * tid;
    float hw[8];
    *(float4*)&hw[0] = *(const float4*)&hpad[base];
    float acc[4] = {0.f, 0.f, 0.f, 0.f};
    const float* xp = symbols + s * DD;
#pragma unroll
    for (int c = 0; c < 16; c++) {
        *(float4*)&hw[4] = *(const float4*)&hpad[base + 4 * (c + 1)];
        const float x0 = xp[4 * c + 0];
        const float x1 = xp[4 * c + 1];
        const float x2 = xp[4 * c + 2];
        const float x3 = xp[4 * c + 3];
        acc[0] += x0 * hw[4]; acc[0] += x1 * hw[5]; acc[0] += x2 * hw[6]; acc[0] += x3 * hw[7];
        acc[1] += x0 * hw[3]; acc[1] += x1 * hw[4]; acc[1] += x2 * hw[5]; acc[1] += x3 * hw[6];
        acc[2] += x0 * hw[2]; acc[2] += x1 * hw[3]; acc[2] += x2 * hw[4]; acc[2] += x3 * hw[5];
        acc[3] += x0 * hw[1]; acc[3] += x1 * hw[2]; acc[3] += x2 * hw[3]; acc[3] += x3 * hw[4];
        hw[0] = hw[4]; hw[1] = hw[5]; hw[2] = hw[6]; hw[3] = hw[7];
    }

    float ys[4];
    float lsum = 0.f, lsq = 0.f;
#pragma unroll
    for (int j = 0; j < 4; j++) {
        ys[j] = silu_f(acc[j]);
        lsum += ys[j]; lsq += ys[j] * ys[j];
    }
    lsum = wave64_sum_l63(lsum);
    lsq  = wave64_sum_l63(lsq);
    if (lane == 63) { red[wave][0] = lsum; red[wave][1] = lsq; }
    __syncthreads();
    float s0 = 0.f, s1 = 0.f;
#pragma unroll
    for (int w = 0; w < 4; w++) { s0 += red[w][0]; s1 += red[w][1]; }
    const float mean = s0 * (1.f / VSA);
    const float rstd = rsqrtf(s1 * (1.f / VSA) - mean * mean + LNE);

    const float4 g4 = *(const float4*)&gamma[4 * tid];
    const float4 b4 = *(const float4*)&beta[4 * tid];
    float4 o;
    o.x = (ys[0] - mean) * rstd * g4.x + b4.x;
    o.y = (ys[1] - mean) * rstd * g4.y + b4.y;
    o.z = (ys[2] - mean) * rstd * g4.z + b4.z;
    o.w = (ys[3] - mean) * rstd * g4.w + b4.w;
    *(float4*)&sp[s * VSA + 4 * tid] = o;
}

// ------- Kernel 2: NB=2 batches per block --------------------------------
// R9 post-mortem: kernel regressed 93->130us (VALUBusy 71->41) because the
// slimmed silu (rcp) left too few insts inside the per-s sched_barrier
// walls to cover v_exp/v_rcp (TRANS, quarter-rate) + 4 serial DPP chains;
// R8's fat IEEE-div silu had been hiding that latency.  Wall is now
// latency-bound (155 = 130 x 1.19), so fix the stall at EQUAL inst count:
// R10 defers ALL silu+LN reductions out of the conv: 5 conv bodies run
// back-to-back (SGB quotas bound in-flight loads; one sched_barrier per
// s-start as spill insurance), then ONE batched reduce phase with 20
// independent silu2 + 20 DPP chains -> cross-s ILP hides TRANS/DPP latency.
// Bit-identical math (pure reordering across independent values).
__global__ __launch_bounds__(NT, 2)
void main_kernel(const float* __restrict__ values, const float* __restrict__ hpadG,
                 const float* __restrict__ sp, const float* __restrict__ gamma,
                 const float* __restrict__ beta, float* __restrict__ out)
{
    __shared__ __align__(16) float hs[SS * PW];       // 21.8 KB padded h
    __shared__ __align__(16) float xsI[SS][DD][NB];   // 2.5 KB values, nb-interleaved
    __shared__ float red[SS][NB][4][2];
    __shared__ int   scorered[NB][4][SS * SS];
    __shared__ __align__(8) float wbufP[SS * SS][2];  // softmax weights, nb-interleaved

    const int tid = threadIdx.x;
    const int lane = tid & 63, wave = tid >> 6;
    const int b0 = blockIdx.x * NB;
    const int base = 1020 - 4 * tid;

    // stage padded h: 5460 floats = 1365 float4, coalesced
    for (int i = tid; i < (SS * PW) / 4; i += NT)
        ((float4*)hs)[i] = ((const float4*)hpadG)[i];

    // stage values nb-interleaved: xsI[s][d] = {v[b0][s][d], v[b0+1][s][d]}
    for (int i = tid; i < SS * DD; i += NT) {
        v2f v;
        v.x = values[(size_t)(b0 + 0) * (SS * DD) + i];
        v.y = values[(size_t)(b0 + 1) * (SS * DD) + i];
        ((v2f*)xsI)[i] = v;
    }
    __syncthreads();

    v2f vpP[SS][4];   // raw conv accumulators, then silu->LN in place

    // --- conv phase: 5 s bodies back-to-back, accumulate into vpP directly
#pragma unroll
    for (int s = 0; s < SS; s++) {
        __builtin_amdgcn_sched_barrier(0);   // bound cross-s load hoisting
        const float* hp = hs + s * PW + base;
        const v2f*   xp = (const v2f*)&xsI[s][0][0];
        // preload c=0 operands (4 ds_read_b128)
        float4 hLo = *(const float4*)hp;          // taps 4c+0..3
        float4 hHi = *(const float4*)(hp + 4);    // taps 4c+4..7
        float4 xq0 = *(const float4*)(xp + 0);    // pairs d=0,1
        float4 xq1 = *(const float4*)(xp + 2);    // pairs d=2,3
        v2f x0 = {xq0.x, xq0.y}, x1 = {xq0.z, xq0.w};
        v2f x2 = {xq1.x, xq1.y}, x3 = {xq1.z, xq1.w};
        v2f a0 = {}, a1 = {}, a2 = {}, a3 = {};
#pragma unroll
        for (int c = 0; c < 16; c++) {
            // prefetch c+1 operands (3 ds_read_b128: 1 per-lane h, 2 uniform x)
            float4 hNx = {}, xq0n = {}, xq1n = {};
            if (c < 15) {
                hNx  = *(const float4*)(hp + 4 * c + 8);     // max idx 1091 < PW
                xq0n = *(const float4*)(xp + 4 * c + 4);     // pairs d=4c+4,4c+5
                xq1n = *(const float4*)(xp + 4 * c + 6);     // pairs d=4c+6,4c+7
            }
            // 16 pk FMAs for step c; per-lane chain order == scalar version
            a0 = fma2(x0, hHi.x, a0); a0 = fma2(x1, hHi.y, a0);
            a0 = fma2(x2, hHi.z, a0); a0 = fma2(x3, hHi.w, a0);
            a1 = fma2(x0, hLo.w, a1); a1 = fma2(x1, hHi.x, a1);
            a1 = fma2(x2, hHi.y, a1); a1 = fma2(x3, hHi.z, a1);
            a2 = fma2(x0, hLo.z, a2); a2 = fma2(x1, hLo.w, a2);
            a2 = fma2(x2, hHi.x, a2); a2 = fma2(x3, hHi.y, a2);
            a3 = fma2(x0, hLo.y, a3); a3 = fma2(x1, hLo.z, a3);
            a3 = fma2(x2, hLo.w, a3); a3 = fma2(x3, hHi.x, a3);
            // quota groups: 3 DS_READ (c+1 loads) BEFORE the 16 pk FMAs
            if (c < 15)
                __builtin_amdgcn_sched_group_barrier(0x100 /*DS_READ*/, 3, 0);
            __builtin_amdgcn_sched_group_barrier(0x2 /*VALU*/, 16, 0);
            // window rotate: renamed away under full unroll
            hLo = hHi; hHi = hNx;
            x0 = (v2f){xq0n.x, xq0n.y}; x1 = (v2f){xq0n.z, xq0n.w};
            x2 = (v2f){xq1n.x, xq1n.y}; x3 = (v2f){xq1n.z, xq1n.w};
        }
        vpP[s][0] = a0; vpP[s][1] = a1; vpP[s][2] = a2; vpP[s][3] = a3;
    }

    // --- batched reduce phase: 20 silu2 + 20 DPP chains, full ILP
#pragma unroll
    for (int s = 0; s < SS; s++) {
        v2f y0 = silu2(vpP[s][0]), y1 = silu2(vpP[s][1]);
        v2f y2 = silu2(vpP[s][2]), y3 = silu2(vpP[s][3]);
        vpP[s][0] = y0; vpP[s][1] = y1; vpP[s][2] = y2; vpP[s][3] = y3;
        v2f ls = ((y0 + y1) + y2) + y3;
        v2f lq = y0 * y0;
        lq = fma2v(y1, y1, lq); lq = fma2v(y2, y2, lq); lq = fma2v(y3, y3, lq);
        const float S0 = wave64_sum_l63(ls.x), Q0 = wave64_sum_l63(lq.x);
        const float S1 = wave64_sum_l63(ls.y), Q1 = wave64_sum_l63(lq.y);
        if (lane == 63) {
            red[s][0][wave][0] = S0; red[s][0][wave][1] = Q0;
            red[s][1][wave][0] = S1; red[s][1][wave][1] = Q1;
        }
    }
    __syncthreads();

    // LayerNorm epilogue: pk over the nb pair
    const float4 g4 = *(const float4*)&gamma[4 * tid];
    const float4 b4 = *(const float4*)&beta[4 * tid];
#pragma unroll
    for (int s = 0; s < SS; s++) {
        float s00 = 0.f, q00 = 0.f, s01 = 0.f, q01 = 0.f;
#pragma unroll
        for (int w = 0; w < 4; w++) {
            s00 += red[s][0][w][0]; q00 += red[s][0][w][1];
            s01 += red[s][1][w][0]; q01 += red[s][1][w][1];
        }
        const float m0 = s00 * (1.f / VSA), m1 = s01 * (1.f / VSA);
        const float r0 = rsqrtf(q00 * (1.f / VSA) - m0 * m0 + LNE);
        const float r1 = rsqrtf(q01 * (1.f / VSA) - m1 * m1 + LNE);
        v2f mean2; mean2.x = m0; mean2.y = m1;
        v2f rstd2; rstd2.x = r0; rstd2.y = r1;
        vpP[s][0] = fma2((vpP[s][0] - mean2) * rstd2, g4.x, splat2(b4.x));
        vpP[s][1] = fma2((vpP[s][1] - mean2) * rstd2, g4.y, splat2(b4.y));
        vpP[s][2] = fma2((vpP[s][2] - mean2) * rstd2, g4.z, splat2(b4.z));
        vpP[s][3] = fma2((vpP[s][3] - mean2) * rstd2, g4.w, splat2(b4.w));
    }

    // sp fragments (batch-independent, L1/L2-hot)
    float sp4[SS][4];
#pragma unroll
    for (int i = 0; i < SS; i++)
        *(float4*)&sp4[i][0] = *(const float4*)&sp[i * VSA + 4 * tid];

    // scores via ballot: sign(a)*sign(b) = 1 - 2*[signbits differ]
    // sign(vp+sp) == (vp > -sp); '-' folds into v_cmp input modifier
#pragma unroll
    for (int nb = 0; nb < NB; nb++) {
        int neq[SS * SS];
#pragma unroll
        for (int p = 0; p < SS * SS; p++) neq[p] = 0;
#pragma unroll
        for (int jj = 0; jj < 4; jj++) {
            unsigned long long bvi[SS];
#pragma unroll
            for (int i = 0; i < SS; i++) bvi[i] = __ballot(c2(vpP[i][jj], nb) > 0.f);
#pragma unroll
            for (int j = 0; j < SS; j++) {
                const float sjv = sp4[j][jj];
#pragma unroll
                for (int i = 0; i < SS; i++) {
                    const unsigned long long bs = __ballot(c2(vpP[i][jj], nb) > -sjv);
                    neq[j * SS + i] += (int)__popcll(bvi[i] ^ bs);
                }
            }
        }
        if (lane == 0) {
#pragma unroll
            for (int p = 0; p < SS * SS; p++) scorered[nb][wave][p] = neq[p];
        }
    }
    __syncthreads();

    // softmax over i per (nb, j) — NB*SS threads
    if (tid < NB * SS) {
        const int nb = tid / SS, j = tid - nb * SS;
        float sc[SS];
#pragma unroll
        for (int i = 0; i < SS; i++) {
            const int nq = scorered[nb][0][j * SS + i] + scorered[nb][1][j * SS + i]
                         + scorered[nb][2][j * SS + i] + scorered[nb][3][j * SS + i];
            sc[i] = 1.f - (2.f / VSA) * (float)nq;
        }
        float m = sc[0];
#pragma unroll
        for (int i = 1; i < SS; i++) m = fmaxf(m, sc[i]);
        float e[SS], ssum = 0.f;
#pragma unroll
        for (int i = 0; i < SS; i++) { e[i] = __expf(sc[i] - m); ssum += e[i]; }
        const float inv = rcp_f(ssum);
#pragma unroll
        for (int i = 0; i < SS; i++) wbufP[j * SS + i][nb] = e[i] * inv;
    }
    __syncthreads();

    // out[b][j][t] = silu( (sum_i w[j][i]*vp[i][t]) * sp[j][t] ), pk over nb
    const size_t obase0 = (size_t)(b0 + 0) * SS * VSA + 4 * tid;
    const size_t obase1 = (size_t)(b0 + 1) * SS * VSA + 4 * tid;
#pragma unroll
    for (int j = 0; j < SS; j++) {
        v2f wp[SS];
#pragma unroll
        for (int i = 0; i < SS; i++) wp[i] = *(const v2f*)&wbufP[j * SS + i][0];
        v2f att[4] = {};
#pragma unroll
        for (int i = 0; i < SS; i++) {
#pragma unroll
            for (int e = 0; e < 4; e++) att[e] = fma2v(wp[i], vpP[i][e], att[e]);
        }
        v2f r[4];
#pragma unroll
        for (int e = 0; e < 4; e++) r[e] = silu2(att[e] * splat2(sp4[j][e]));
        v4f o0; o0.x = r[0].x; o0.y = r[1].x; o0.z = r[2].x; o0.w = r[3].x;
        v4f o1; o1.x = r[0].y; o1.y = r[1].y; o1.z = r[2].y; o1.w = r[3].y;
        __builtin_nontemporal_store(o0, (v4f*)&out[obase0 + (size_t)j * VSA]);
        __builtin_nontemporal_store(o1, (v4f*)&out[obase1 + (size_t)j * VSA]);
    }
}

extern "C" void kernel_launch(void* const* d_in, const int* in_sizes, int n_in,
                              void* d_out, int out_size, void* d_ws, size_t ws_size,
                              hipStream_t stream) {
    const float* values  = (const float*)d_in[0];
    const float* h       = (const float*)d_in[1];
    const float* symbols = (const float*)d_in[2];
    const float* gamma   = (const float*)d_in[3];
    const float* beta    = (const float*)d_in[4];
    float* out   = (float*)d_out;
    float* sp    = (float*)d_ws;                 // 5*1024 floats
    float* hpadG = (float*)d_ws + SS * VSA;      // 5*1092 floats (padded h)

    sp_kernel<<<SS, NT, 0, stream>>>(symbols, h, gamma, beta, sp, hpadG);
    main_kernel<<<BB / NB, NT, 0, stream>>>(values, hpadG, sp, gamma, beta, out);
}

// Round 11
// 171.682 us; speedup vs baseline: 3.6273x; 3.6273x over previous
//
#include <hip/hip_runtime.h>
#include <math.h>

#define BB   4096
#define SS   5
#define DD   64
#define HSZ  961
#define VSA  1024
#define NT   256
#define NB   2      // batches per block, packed pairwise (v2f = (nb0,nb1))
#define LNE  1e-3f

// padded h layout: P[r] = h[r-POFF] for r in [POFF, POFF+960], else 0
#define POFF 64
#define PW   1092   // max index accessed = 1091 (incl. +1-iter prefetch); 16B rows

typedef float v4f __attribute__((ext_vector_type(4)));   // native vec for nontemporal
typedef float v2f __attribute__((ext_vector_type(2)));   // packed pair (nb0,nb1)

__device__ __forceinline__ float rcp_f(float x) { return __builtin_amdgcn_rcpf(x); }
__device__ __forceinline__ float silu_f(float x) { return x * rcp_f(1.f + __expf(-x)); }
__device__ __forceinline__ v2f splat2(float x) { v2f r; r.x = x; r.y = x; return r; }
__device__ __forceinline__ v2f fma2(v2f a, float b, v2f c) {
    return __builtin_elementwise_fma(a, splat2(b), c);   // v_pk_fma_f32
}
__device__ __forceinline__ v2f fma2v(v2f a, v2f b, v2f c) {
    return __builtin_elementwise_fma(a, b, c);
}
__device__ __forceinline__ v2f silu2(v2f x) {            // both nb at once
    v2f e; e.x = __expf(-x.x); e.y = __expf(-x.y);
    v2f d = e + splat2(1.f);
    v2f rc; rc.x = rcp_f(d.x); rc.y = rcp_f(d.y);
    return x * rc;
}
// component select with compile-time nb (all uses under full unroll)
__device__ __forceinline__ float c2(v2f v, int nb) { return nb == 0 ? v.x : v.y; }

// ---- DPP wave64 sum: pure-VALU reduction, no lgkmcnt traffic ----
template <int CTRL>
__device__ __forceinline__ float dpp_add(float x) {
    int t = __builtin_amdgcn_update_dpp(0, __builtin_bit_cast(int, x),
                                        CTRL, 0xf, 0xf, false);
    return x + __builtin_bit_cast(float, t);
}
__device__ __forceinline__ float wave64_sum_l63(float x) {
    x = dpp_add<0x111>(x);  // row_shr:1
    x = dpp_add<0x112>(x);  // row_shr:2
    x = dpp_add<0x114>(x);  // row_shr:4
    x = dpp_add<0x118>(x);  // row_shr:8
    x = dpp_add<0x142>(x);  // row_bcast:15
    x = dpp_add<0x143>(x);  // row_bcast:31
    return x;
}

// ---- Kernel 1: sp = LN(silu(conv(symbols,h))); also emit zero-padded h ----
__global__ __launch_bounds__(NT)
void sp_kernel(const float* __restrict__ symbols, const float* __restrict__ h,
               const float* __restrict__ gamma, const float* __restrict__ beta,
               float* __restrict__ sp, float* __restrict__ hpadG)
{
    __shared__ float hpad[PW];
    __shared__ float red[4][2];
    const int s = blockIdx.x;
    const int tid = threadIdx.x;
    const int lane = tid & 63, wave = tid >> 6;

    for (int r = tid; r < PW; r += NT) {
        const float v = (r >= POFF && r <= POFF + 960) ? h[s * HSZ + (r - POFF)] : 0.f;
        hpad[r] = v;
        hpadG[s * PW + r] = v;        // padded copy for main_kernel
    }
    __syncthreads();

    const int base = 1020 - 4 * tid;
    float hw[8];
    *(float4*)&hw[0] = *(const float4*)&hpad[base];
    float acc[4] = {0.f, 0.f, 0.f, 0.f};
    const float* xp = symbols + s * DD;
#pragma unroll
    for (int c = 0; c < 16; c++) {
        *(float4*)&hw[4] = *(const float4*)&hpad[base + 4 * (c + 1)];
        const float x0 = xp[4 * c + 0];
        const float x1 = xp[4 * c + 1];
        const float x2 = xp[4 * c + 2];
        const float x3 = xp[4 * c + 3];
        acc[0] += x0 * hw[4]; acc[0] += x1 * hw[5]; acc[0] += x2 * hw[6]; acc[0] += x3 * hw[7];
        acc[1] += x0 * hw[3]; acc[1] += x1 * hw[4]; acc[1] += x2 * hw[5]; acc[1] += x3 * hw[6];
        acc[2] += x0 * hw[2]; acc[2] += x1 * hw[3]; acc[2] += x2 * hw[4]; acc[2] += x3 * hw[5];
        acc[3] += x0 * hw[1]; acc[3] += x1 * hw[2]; acc[3] += x2 * hw[3]; acc[3] += x3 * hw[4];
        hw[0] = hw[4]; hw[1] = hw[5]; hw[2] = hw[6]; hw[3] = hw[7];
    }

    float ys[4];
    float lsum = 0.f, lsq = 0.f;
#pragma unroll
    for (int j = 0; j < 4; j++) {
        ys[j] = silu_f(acc[j]);
        lsum += ys[j]; lsq += ys[j] * ys[j];
    }
    lsum = wave64_sum_l63(lsum);
    lsq  = wave64_sum_l63(lsq);
    if (lane == 63) { red[wave][0] = lsum; red[wave][1] = lsq; }
    __syncthreads();
    float s0 = 0.f, s1 = 0.f;
#pragma unroll
    for (int w = 0; w < 4; w++) { s0 += red[w][0]; s1 += red[w][1]; }
    const float mean = s0 * (1.f / VSA);
    const float rstd = rsqrtf(s1 * (1.f / VSA) - mean * mean + LNE);

    const float4 g4 = *(const float4*)&gamma[4 * tid];
    const float4 b4 = *(const float4*)&beta[4 * tid];
    float4 o;
    o.x = (ys[0] - mean) * rstd * g4.x + b4.x;
    o.y = (ys[1] - mean) * rstd * g4.y + b4.y;
    o.z = (ys[2] - mean) * rstd * g4.z + b4.z;
    o.w = (ys[3] - mean) * rstd * g4.w + b4.w;
    *(float4*)&sp[s * VSA + 4 * tid] = o;
}

// ------- Kernel 2: NB=2 batches per block --------------------------------
// R10 post-mortem: deferring ALL reduces with the reduce loop UNFENCED let
// the scheduler interleave 5 reduce iterations + hoist downstream loads ->
// spill (VGPR 128, WRITE 1.24 GB).  Rule: any multi-iteration region with
// cross-iteration ILP must be explicitly fenced on this compiler.
// R11 = R9 + minimum-dose ILP: reduce in PAIRS of s-bodies, fences at every
// boundary: [SB] conv s [SB] conv s+1 [SB] reduce(s);reduce(s+1) [SB].
// 2-way cross-s ILP in the TRANS/DPP region at +8 VGPRs bounded pressure.
// red stored as packed v2f {S,Q} (saves 40 scalar LDS reads in LN).
// Math bit-identical to R9.

#define SB() __builtin_amdgcn_sched_barrier(0)

#define CONV_S(s_) { \
    const float* hp = hs + (s_) * PW + base; \
    const v2f*   xp = (const v2f*)&xsI[(s_)][0][0]; \
    float4 hLo = *(const float4*)hp; \
    float4 hHi = *(const float4*)(hp + 4); \
    float4 xq0 = *(const float4*)(xp + 0); \
    float4 xq1 = *(const float4*)(xp + 2); \
    v2f x0 = {xq0.x, xq0.y}, x1 = {xq0.z, xq0.w}; \
    v2f x2 = {xq1.x, xq1.y}, x3 = {xq1.z, xq1.w}; \
    v2f a0 = {}, a1 = {}, a2 = {}, a3 = {}; \
    _Pragma("unroll") \
    for (int c = 0; c < 16; c++) { \
        float4 hNx = {}, xq0n = {}, xq1n = {}; \
        if (c < 15) { \
            hNx  = *(const float4*)(hp + 4 * c + 8); \
            xq0n = *(const float4*)(xp + 4 * c + 4); \
            xq1n = *(const float4*)(xp + 4 * c + 6); \
        } \
        a0 = fma2(x0, hHi.x, a0); a0 = fma2(x1, hHi.y, a0); \
        a0 = fma2(x2, hHi.z, a0); a0 = fma2(x3, hHi.w, a0); \
        a1 = fma2(x0, hLo.w, a1); a1 = fma2(x1, hHi.x, a1); \
        a1 = fma2(x2, hHi.y, a1); a1 = fma2(x3, hHi.z, a1); \
        a2 = fma2(x0, hLo.z, a2); a2 = fma2(x1, hLo.w, a2); \
        a2 = fma2(x2, hHi.x, a2); a2 = fma2(x3, hHi.y, a2); \
        a3 = fma2(x0, hLo.y, a3); a3 = fma2(x1, hLo.z, a3); \
        a3 = fma2(x2, hLo.w, a3); a3 = fma2(x3, hHi.x, a3); \
        if (c < 15) \
            __builtin_amdgcn_sched_group_barrier(0x100 /*DS_READ*/, 3, 0); \
        __builtin_amdgcn_sched_group_barrier(0x2 /*VALU*/, 16, 0); \
        hLo = hHi; hHi = hNx; \
        x0 = (v2f){xq0n.x, xq0n.y}; x1 = (v2f){xq0n.z, xq0n.w}; \
        x2 = (v2f){xq1n.x, xq1n.y}; x3 = (v2f){xq1n.z, xq1n.w}; \
    } \
    vpP[(s_)][0] = a0; vpP[(s_)][1] = a1; \
    vpP[(s_)][2] = a2; vpP[(s_)][3] = a3; \
}

#define RED_S(s_) { \
    v2f y0 = silu2(vpP[(s_)][0]), y1 = silu2(vpP[(s_)][1]); \
    v2f y2 = silu2(vpP[(s_)][2]), y3 = silu2(vpP[(s_)][3]); \
    vpP[(s_)][0] = y0; vpP[(s_)][1] = y1; \
    vpP[(s_)][2] = y2; vpP[(s_)][3] = y3; \
    v2f ls = ((y0 + y1) + y2) + y3; \
    v2f lq = y0 * y0; \
    lq = fma2v(y1, y1, lq); lq = fma2v(y2, y2, lq); lq = fma2v(y3, y3, lq); \
    const float S0 = wave64_sum_l63(ls.x), Q0 = wave64_sum_l63(lq.x); \
    const float S1 = wave64_sum_l63(ls.y), Q1 = wave64_sum_l63(lq.y); \
    if (lane == 63) { \
        v2f r0; r0.x = S0; r0.y = Q0; redP[(s_)][0][wave] = r0; \
        v2f r1; r1.x = S1; r1.y = Q1; redP[(s_)][1][wave] = r1; \
    } \
}

__global__ __launch_bounds__(NT, 2)
void main_kernel(const float* __restrict__ values, const float* __restrict__ hpadG,
                 const float* __restrict__ sp, const float* __restrict__ gamma,
                 const float* __restrict__ beta, float* __restrict__ out)
{
    __shared__ __align__(16) float hs[SS * PW];       // 21.8 KB padded h
    __shared__ __align__(16) float xsI[SS][DD][NB];   // 2.5 KB values, nb-interleaved
    __shared__ __align__(8)  v2f   redP[SS][NB][4];   // {sum, sumsq} per wave
    __shared__ int   scorered[NB][4][SS * SS];
    __shared__ __align__(8) float wbufP[SS * SS][2];  // softmax weights, nb-interleaved

    const int tid = threadIdx.x;
    const int lane = tid & 63, wave = tid >> 6;
    const int b0 = blockIdx.x * NB;
    const int base = 1020 - 4 * tid;

    // stage padded h: 5460 floats = 1365 float4, coalesced
    for (int i = tid; i < (SS * PW) / 4; i += NT)
        ((float4*)hs)[i] = ((const float4*)hpadG)[i];

    // stage values nb-interleaved: xsI[s][d] = {v[b0][s][d], v[b0+1][s][d]}
    for (int i = tid; i < SS * DD; i += NT) {
        v2f v;
        v.x = values[(size_t)(b0 + 0) * (SS * DD) + i];
        v.y = values[(size_t)(b0 + 1) * (SS * DD) + i];
        ((v2f*)xsI)[i] = v;
    }
    __syncthreads();

    v2f vpP[SS][4];   // conv accumulators -> silu -> LN, in place

    // --- fenced pair-pipelined conv + reduce ---
    SB();
    CONV_S(0);
    SB();
    CONV_S(1);
    SB();
    RED_S(0);
    RED_S(1);
    SB();
    CONV_S(2);
    SB();
    CONV_S(3);
    SB();
    RED_S(2);
    RED_S(3);
    SB();
    CONV_S(4);
    SB();
    RED_S(4);
    SB();
    __syncthreads();

    // LayerNorm epilogue: pk over the nb pair; redP read as v2f
    const float4 g4 = *(const float4*)&gamma[4 * tid];
    const float4 b4 = *(const float4*)&beta[4 * tid];
#pragma unroll
    for (int s = 0; s < SS; s++) {
        v2f t0 = ((redP[s][0][0] + redP[s][0][1]) + redP[s][0][2]) + redP[s][0][3];
        v2f t1 = ((redP[s][1][0] + redP[s][1][1]) + redP[s][1][2]) + redP[s][1][3];
        const float m0 = t0.x * (1.f / VSA), m1 = t1.x * (1.f / VSA);
        const float r0 = rsqrtf(t0.y * (1.f / VSA) - m0 * m0 + LNE);
        const float r1 = rsqrtf(t1.y * (1.f / VSA) - m1 * m1 + LNE);
        v2f mean2; mean2.x = m0; mean2.y = m1;
        v2f rstd2; rstd2.x = r0; rstd2.y = r1;
        vpP[s][0] = fma2((vpP[s][0] - mean2) * rstd2, g4.x, splat2(b4.x));
        vpP[s][1] = fma2((vpP[s][1] - mean2) * rstd2, g4.y, splat2(b4.y));
        vpP[s][2] = fma2((vpP[s][2] - mean2) * rstd2, g4.z, splat2(b4.z));
        vpP[s][3] = fma2((vpP[s][3] - mean2) * rstd2, g4.w, splat2(b4.w));
    }

    // sp fragments (batch-independent, L1/L2-hot)
    float sp4[SS][4];
#pragma unroll
    for (int i = 0; i < SS; i++)
        *(float4*)&sp4[i][0] = *(const float4*)&sp[i * VSA + 4 * tid];

    // scores via ballot: sign(a)*sign(b) = 1 - 2*[signbits differ]
    // sign(vp+sp) == (vp > -sp); '-' folds into v_cmp input modifier
#pragma unroll
    for (int nb = 0; nb < NB; nb++) {
        int neq[SS * SS];
#pragma unroll
        for (int p = 0; p < SS * SS; p++) neq[p] = 0;
#pragma unroll
        for (int jj = 0; jj < 4; jj++) {
            unsigned long long bvi[SS];
#pragma unroll
            for (int i = 0; i < SS; i++) bvi[i] = __ballot(c2(vpP[i][jj], nb) > 0.f);
#pragma unroll
            for (int j = 0; j < SS; j++) {
                const float sjv = sp4[j][jj];
#pragma unroll
                for (int i = 0; i < SS; i++) {
                    const unsigned long long bs = __ballot(c2(vpP[i][jj], nb) > -sjv);
                    neq[j * SS + i] += (int)__popcll(bvi[i] ^ bs);
                }
            }
        }
        if (lane == 0) {
#pragma unroll
            for (int p = 0; p < SS * SS; p++) scorered[nb][wave][p] = neq[p];
        }
    }
    __syncthreads();

    // softmax over i per (nb, j) — NB*SS threads
    if (tid < NB * SS) {
        const int nb = tid / SS, j = tid - nb * SS;
        float sc[SS];
#pragma unroll
        for (int i = 0; i < SS; i++) {
            const int nq = scorered[nb][0][j * SS + i] + scorered[nb][1][j * SS + i]
                         + scorered[nb][2][j * SS + i] + scorered[nb][3][j * SS + i];
            sc[i] = 1.f - (2.f / VSA) * (float)nq;
        }
        float m = sc[0];
#pragma unroll
        for (int i = 1; i < SS; i++) m = fmaxf(m, sc[i]);
        float e[SS], ssum = 0.f;
#pragma unroll
        for (int i = 0; i < SS; i++) { e[i] = __expf(sc[i] - m); ssum += e[i]; }
        const float inv = rcp_f(ssum);
#pragma unroll
        for (int i = 0; i < SS; i++) wbufP[j * SS + i][nb] = e[i] * inv;
    }
    __syncthreads();

    // out[b][j][t] = silu( (sum_i w[j][i]*vp[i][t]) * sp[j][t] ), pk over nb
    const size_t obase0 = (size_t)(b0 + 0) * SS * VSA + 4 * tid;
    const size_t obase1 = (size_t)(b0 + 1) * SS * VSA + 4 * tid;
#pragma unroll
    for (int j = 0; j < SS; j++) {
        v2f wp[SS];
#pragma unroll
        for (int i = 0; i < SS; i++) wp[i] = *(const v2f*)&wbufP[j * SS + i][0];
        v2f att[4] = {};
#pragma unroll
        for (int i = 0; i < SS; i++) {
#pragma unroll
            for (int e = 0; e < 4; e++) att[e] = fma2v(wp[i], vpP[i][e], att[e]);
        }
        v2f r[4];
#pragma unroll
        for (int e = 0; e < 4; e++) r[e] = silu2(att[e] * splat2(sp4[j][e]));
        v4f o0; o0.x = r[0].x; o0.y = r[1].x; o0.z = r[2].x; o0.w = r[3].x;
        v4f o1; o1.x = r[0].y; o1.y = r[1].y; o1.z = r[2].y; o1.w = r[3].y;
        __builtin_nontemporal_store(o0, (v4f*)&out[obase0 + (size_t)j * VSA]);
        __builtin_nontemporal_store(o1, (v4f*)&out[obase1 + (size_t)j * VSA]);
    }
}

extern "C" void kernel_launch(void* const* d_in, const int* in_sizes, int n_in,
                              void* d_out, int out_size, void* d_ws, size_t ws_size,
                              hipStream_t stream) {
    const float* values  = (const float*)d_in[0];
    const float* h       = (const float*)d_in[1];
    const float* symbols = (const float*)d_in[2];
    const float* gamma   = (const float*)d_in[3];
    const float* beta    = (const float*)d_in[4];
    float* out   = (float*)d_out;
    float* sp    = (float*)d_ws;                 // 5*1024 floats
    float* hpadG = (float*)d_ws + SS * VSA;      // 5*1092 floats (padded h)

    sp_kernel<<<SS, NT, 0, stream>>>(symbols, h, gamma, beta, sp, hpadG);
    main_kernel<<<BB / NB, NT, 0, stream>>>(values, hpadG, sp, gamma, beta, out);
}